// Round 4
// baseline (1231.217 us; speedup 1.0000x reference)
//
#include <hip/hip_runtime.h>
#include <math.h>

#define FB 512
#define TB 256
#define PLANE (FB * TB)
typedef long long i64;
typedef _Float16 f16;
typedef _Float16 f16x8 __attribute__((ext_vector_type(8)));
typedef _Float16 f16x4 __attribute__((ext_vector_type(4)));
typedef float f32x4 __attribute__((ext_vector_type(4)));

#define MFMA16(a, b, c) __builtin_amdgcn_mfma_f32_16x16x32_f16(a, b, c, 0, 0, 0)

// ---------- Weff = W2 @ W1  (f32 accum, f16 out)
__global__ __launch_bounds__(256) void k_weff(const float* __restrict__ W1,
                                              const float* __restrict__ W2,
                                              f16* __restrict__ Weff) {
    const int m = blockIdx.y * 4 + (threadIdx.x >> 6);
    const int k = blockIdx.x * 64 + (threadIdx.x & 63);
    const float* w2r = W2 + (i64)m * FB;
    float acc = 0.f;
#pragma unroll 4
    for (int j = 0; j < FB; ++j) acc = fmaf(w2r[j], W1[(i64)j * FB + k], acc);
    Weff[(i64)m * FB + k] = (f16)acc;
}

// ---------- beff = W2 @ b1 + b2 (f32)
__global__ __launch_bounds__(256) void k_beff(const float* __restrict__ W2,
                                              const float* __restrict__ b1,
                                              const float* __restrict__ b2,
                                              float* __restrict__ beff) {
    const int m = blockIdx.x * 256 + threadIdx.x;
    const float* w2r = W2 + (i64)m * FB;
    float acc = b2[m];
#pragma unroll 4
    for (int k = 0; k < FB; ++k) acc = fmaf(w2r[k], b1[k], acc);
    beff[m] = acc;
}

// ---------- x f32 [f][t] -> xh f16 transposed [t][f], per plane, via LDS
__global__ __launch_bounds__(256) void k_transpose_cvt(const float* __restrict__ X,
                                                       f16* __restrict__ O) {
    __shared__ float ld[64][65];
    const int p = blockIdx.z;
    const float* src = X + (i64)p * PLANE;
    f16* dst = O + (i64)p * PLANE;
    const int f0 = blockIdx.y * 64, t0 = blockIdx.x * 64;
    const int tid = threadIdx.x;
    const int lrr = tid >> 4, lc = (tid & 15) * 4;
#pragma unroll
    for (int i = 0; i < 4; ++i) {
        float4 v = *(const float4*)&src[(i64)(f0 + lrr + i * 16) * TB + t0 + lc];
        ld[lrr + i * 16][lc + 0] = v.x;
        ld[lrr + i * 16][lc + 1] = v.y;
        ld[lrr + i * 16][lc + 2] = v.z;
        ld[lrr + i * 16][lc + 3] = v.w;
    }
    __syncthreads();
    const int tr = tid >> 2, fq = tid & 3;
#pragma unroll
    for (int i = 0; i < 4; ++i) {
        const int fl = fq * 16 + i * 4;
        f16x4 o;
#pragma unroll
        for (int j = 0; j < 4; ++j) o[j] = (f16)ld[fl + j][tr];
        *(f16x4*)&dst[(i64)(t0 + tr) * FB + f0 + fl] = o;
    }
}

// ---------- real MFMA GEMM: Out[t][m] (f16) = sum_k A[m][k]*In[t][k] + bias[m]
__global__ __launch_bounds__(256, 2) void k_rgemm(const f16* __restrict__ A,
                                                  const f16* __restrict__ In,
                                                  const float* __restrict__ bias,
                                                  f16* __restrict__ Out) {
    __shared__ f16 Asx[128][40], Bsx[128][40];
    const int slab = blockIdx.z;
    const f16* Bsrc = In + (i64)slab * PLANE;
    f16* Odst = Out + (i64)slab * PLANE;
    const int t0 = blockIdx.x * 128, m0 = blockIdx.y * 128;
    const int tid = threadIdx.x;
    const int wave = tid >> 6, lane = tid & 63;
    const int wm = wave >> 1, wn = wave & 1;
    const int lr = lane & 15, lg = lane >> 4;
    const int srow = tid >> 2, sgrp = (tid & 3) * 8;

    f32x4 acc[4][4] = {};
    f16x8 nA[2], nB[2];
#pragma unroll
    for (int i = 0; i < 2; ++i) {
        const int row = i * 64 + srow;
        nA[i] = *(const f16x8*)(A + (i64)(m0 + row) * FB + sgrp);
        nB[i] = *(const f16x8*)(Bsrc + (i64)(t0 + row) * FB + sgrp);
    }
#pragma unroll
    for (int i = 0; i < 2; ++i) {
        const int row = i * 64 + srow;
        *(f16x8*)&Asx[row][sgrp] = nA[i];
        *(f16x8*)&Bsx[row][sgrp] = nB[i];
    }
    __syncthreads();

#pragma unroll 1
    for (int kt = 0; kt < 16; ++kt) {
        if (kt < 15) {
            const int k0 = (kt + 1) * 32;
#pragma unroll
            for (int i = 0; i < 2; ++i) {
                const int row = i * 64 + srow;
                nA[i] = *(const f16x8*)(A + (i64)(m0 + row) * FB + k0 + sgrp);
                nB[i] = *(const f16x8*)(Bsrc + (i64)(t0 + row) * FB + k0 + sgrp);
            }
        }
        f16x8 aA[4], bB[4];
#pragma unroll
        for (int mf = 0; mf < 4; ++mf)
            aA[mf] = *(const f16x8*)&Asx[wm * 64 + mf * 16 + lr][lg * 8];
#pragma unroll
        for (int nf = 0; nf < 4; ++nf)
            bB[nf] = *(const f16x8*)&Bsx[wn * 64 + nf * 16 + lr][lg * 8];
#pragma unroll
        for (int nf = 0; nf < 4; ++nf)
#pragma unroll
            for (int mf = 0; mf < 4; ++mf)
                acc[mf][nf] = MFMA16(aA[mf], bB[nf], acc[mf][nf]);
        __syncthreads();
        if (kt < 15) {
#pragma unroll
            for (int i = 0; i < 2; ++i) {
                const int row = i * 64 + srow;
                *(f16x8*)&Asx[row][sgrp] = nA[i];
                *(f16x8*)&Bsx[row][sgrp] = nB[i];
            }
        }
        __syncthreads();
    }

#pragma unroll
    for (int mf = 0; mf < 4; ++mf) {
        const int m = m0 + wm * 64 + mf * 16 + lg * 4;
        const float4 bv = *(const float4*)&bias[m];
        const float bb[4] = {bv.x, bv.y, bv.z, bv.w};
#pragma unroll
        for (int nf = 0; nf < 4; ++nf) {
            const int t = t0 + wn * 64 + nf * 16 + lr;
            f16x4 o;
#pragma unroll
            for (int r = 0; r < 4; ++r) o[r] = (f16)(acc[mf][nf][r] + bb[r]);
            *(f16x4*)&Odst[(i64)t * FB + m] = o;
        }
    }
}

// ================= fused softmax + IDFT/mul/DFT (512-pt FFT per wave) ========
// p = 8*lane + j. DIF (W+) leaves bit-reversed order; pointwise product in
// scrambled order; DIT (W-) consumes rev order, emits natural.
// Twiddles: one sincos per cross stage + constant-angle rotation per j.

#define TWO_PI_OVER_512 0.012271846303085129f
#define R2C 0.70710678118654752f

__device__ __forceinline__ void bfly_dif(float& ar, float& ai, float& br, float& bi,
                                         float wc, float ws) {
    float dr = ar - br, di = ai - bi;
    ar = ar + br; ai = ai + bi;
    br = dr * wc - di * ws;
    bi = dr * ws + di * wc;
}
__device__ __forceinline__ void bfly_dit(float& ar, float& ai, float& br, float& bi,
                                         float wc, float ws) {
    float tr = br * wc - bi * ws;
    float ti = br * ws + bi * wc;
    br = ar - tr; bi = ai - ti;
    ar = ar + tr; ai = ai + ti;
}

// cross DIF stage: result_lo = mine+partner ; result_hi = (partner-mine)*W+
__device__ __forceinline__ void dif_cross2(float re[8], float im[8], int lane, int M,
                                           float mul, float SC, float SS) {
    const bool hi = (lane & M) != 0;
    const float sgn = hi ? -1.f : 1.f;
    const float th0 = TWO_PI_OVER_512 * mul * (float)(8 * (lane & (M - 1)));
    float s0, c0;
    __sincosf(th0, &s0, &c0);
    float c = hi ? c0 : 1.f;
    float s = hi ? s0 : 0.f;
    const float stC = hi ? SC : 1.f;
    const float stS = hi ? SS : 0.f;
#pragma unroll
    for (int j = 0; j < 8; ++j) {
        float pr = __shfl_xor(re[j], M);
        float pi = __shfl_xor(im[j], M);
        float ur = fmaf(sgn, re[j], pr);
        float ui = fmaf(sgn, im[j], pi);
        re[j] = ur * c - ui * s;
        im[j] = ur * s + ui * c;
        float c2 = c * stC - s * stS;
        s = c * stS + s * stC;
        c = c2;
    }
}

// cross DIT stage: own pre-twiddled by W- on hi lanes, then
// result_lo = own' + partner' ; result_hi = partner' - own'
__device__ __forceinline__ void dit_cross2(float re[8], float im[8], int lane, int M,
                                           float mul, float SC, float SS) {
    const bool hi = (lane & M) != 0;
    const float sgn = hi ? -1.f : 1.f;
    const float th0 = TWO_PI_OVER_512 * mul * (float)(8 * (lane & (M - 1)));
    float s0, c0;
    __sincosf(th0, &s0, &c0);
    float c = hi ? c0 : 1.f;
    float s = hi ? s0 : 0.f;     // actual W- = (c, -s); lo lanes (1,0)
    const float stC = hi ? SC : 1.f;
    const float stS = hi ? SS : 0.f;
#pragma unroll
    for (int j = 0; j < 8; ++j) {
        float vr = re[j] * c + im[j] * s;
        float vi = im[j] * c - re[j] * s;
        float pr = __shfl_xor(vr, M);
        float pi = __shfl_xor(vi, M);
        re[j] = fmaf(sgn, vr, pr);
        im[j] = fmaf(sgn, vi, pi);
        float c2 = c * stC - s * stS;
        s = c * stS + s * stC;
        c = c2;
    }
}

// step constants: cos/sin(2*pi*mul/512)
#define C1  0.99992470183914450f
#define S1  0.012271538285719925f
#define C2  0.99969881869620425f
#define S2  0.024541228522912288f
#define C4  0.99879545620517241f
#define S4  0.049067674327418015f
#define C8  0.99518472667219693f
#define S8  0.098017140329560604f
#define C16 0.98078528040323044f
#define S16 0.19509032201612825f
#define C32 0.92387953251128674f
#define S32 0.38268343236508977f

__device__ __forceinline__ void fft_conj(float re[8], float im[8], int lane) { // F+ DIF
    dif_cross2(re, im, lane, 32, 1.f, C1, S1);
    dif_cross2(re, im, lane, 16, 2.f, C2, S2);
    dif_cross2(re, im, lane, 8, 4.f, C4, S4);
    dif_cross2(re, im, lane, 4, 8.f, C8, S8);
    dif_cross2(re, im, lane, 2, 16.f, C16, S16);
    dif_cross2(re, im, lane, 1, 32.f, C32, S32);
    // h=4 (W+ = e^{+i pi/4 * jlo})
    bfly_dif(re[0], im[0], re[4], im[4], 1.f, 0.f);
    bfly_dif(re[1], im[1], re[5], im[5], R2C, R2C);
    bfly_dif(re[2], im[2], re[6], im[6], 0.f, 1.f);
    bfly_dif(re[3], im[3], re[7], im[7], -R2C, R2C);
    // h=2
    bfly_dif(re[0], im[0], re[2], im[2], 1.f, 0.f);
    bfly_dif(re[1], im[1], re[3], im[3], 0.f, 1.f);
    bfly_dif(re[4], im[4], re[6], im[6], 1.f, 0.f);
    bfly_dif(re[5], im[5], re[7], im[7], 0.f, 1.f);
    // h=1
    bfly_dif(re[0], im[0], re[1], im[1], 1.f, 0.f);
    bfly_dif(re[2], im[2], re[3], im[3], 1.f, 0.f);
    bfly_dif(re[4], im[4], re[5], im[5], 1.f, 0.f);
    bfly_dif(re[6], im[6], re[7], im[7], 1.f, 0.f);
}

__device__ __forceinline__ void fft_fwd(float re[8], float im[8], int lane) { // F- DIT
    // h=1
    bfly_dit(re[0], im[0], re[1], im[1], 1.f, 0.f);
    bfly_dit(re[2], im[2], re[3], im[3], 1.f, 0.f);
    bfly_dit(re[4], im[4], re[5], im[5], 1.f, 0.f);
    bfly_dit(re[6], im[6], re[7], im[7], 1.f, 0.f);
    // h=2 (W- = e^{-i pi/2 * (jlo&1)})
    bfly_dit(re[0], im[0], re[2], im[2], 1.f, 0.f);
    bfly_dit(re[1], im[1], re[3], im[3], 0.f, -1.f);
    bfly_dit(re[4], im[4], re[6], im[6], 1.f, 0.f);
    bfly_dit(re[5], im[5], re[7], im[7], 0.f, -1.f);
    // h=4
    bfly_dit(re[0], im[0], re[4], im[4], 1.f, 0.f);
    bfly_dit(re[1], im[1], re[5], im[5], R2C, -R2C);
    bfly_dit(re[2], im[2], re[6], im[6], 0.f, -1.f);
    bfly_dit(re[3], im[3], re[7], im[7], -R2C, -R2C);
    dit_cross2(re, im, lane, 1, 32.f, C32, S32);
    dit_cross2(re, im, lane, 2, 16.f, C16, S16);
    dit_cross2(re, im, lane, 4, 8.f, C8, S8);
    dit_cross2(re, im, lane, 8, 4.f, C4, S4);
    dit_cross2(re, im, lane, 16, 2.f, C2, S2);
    dit_cross2(re, im, lane, 32, 1.f, C1, S1);
}

__device__ __forceinline__ float wave_max(float v) {
#pragma unroll
    for (int m = 1; m <= 32; m <<= 1) v = fmaxf(v, __shfl_xor(v, m));
    return v;
}
__device__ __forceinline__ float wave_sum(float v) {
#pragma unroll
    for (int m = 1; m <= 32; m <<= 1) v += __shfl_xor(v, m);
    return v;
}

// grid (32 t-blocks, 64 plane-pairs per chunk), block 256 (4 waves, 2 seqs each).
// Writes f32 [t][f] into conv scratch (chunk-local planes), fully coalesced.
__global__ __launch_bounds__(256, 4) void k_fftconv(const f16* __restrict__ xh,
                                                    const f16* __restrict__ logits,
                                                    float* __restrict__ conv,
                                                    int csbase) {
    const int cs = blockIdx.y + csbase;
    const int b = cs >> 4, d = cs & 15;
    const int pre = b * 32 + d;
    const int pim = pre + 16;
    const int chunkoff = (csbase >> 6) * 128;   // plane offset of this chunk
    const int t0 = blockIdx.x * 8;
    const int tid = threadIdx.x;
    const int wave = tid >> 6, lane = tid & 63;

    f16x8 Lhr[2], Lhi[2], Lwr[2], Lwi[2];
#pragma unroll
    for (int it = 0; it < 2; ++it) {
        const i64 row = (i64)(t0 + wave * 2 + it) * FB + lane * 8;
        Lhr[it] = *(const f16x8*)(xh + (i64)pre * PLANE + row);
        Lhi[it] = *(const f16x8*)(xh + (i64)pim * PLANE + row);
        Lwr[it] = *(const f16x8*)(logits + (i64)pre * PLANE + row);
        Lwi[it] = *(const f16x8*)(logits + (i64)pim * PLANE + row);
    }

    float* Cre = conv + (i64)(pre - chunkoff) * PLANE;
    float* Cim = conv + (i64)(pim - chunkoff) * PLANE;

#pragma unroll 1
    for (int it = 0; it < 2; ++it) {
        const int t1 = t0 + wave * 2 + it;
        float hr[8], hi2[8], wr[8], wi[8];
#pragma unroll
        for (int j = 0; j < 8; ++j) {
            hr[j] = (float)Lhr[it][j];
            hi2[j] = (float)Lhi[it][j];
            wr[j] = (float)Lwr[it][j];
            wi[j] = (float)Lwi[it][j];
        }
        // softmax along f for each component plane
        {
            float mx = wr[0];
#pragma unroll
            for (int j = 1; j < 8; ++j) mx = fmaxf(mx, wr[j]);
            mx = wave_max(mx);
            float sm = 0.f;
#pragma unroll
            for (int j = 0; j < 8; ++j) { wr[j] = __expf(wr[j] - mx); sm += wr[j]; }
            sm = wave_sum(sm);
            const float inv = 1.0f / sm;
#pragma unroll
            for (int j = 0; j < 8; ++j) wr[j] *= inv;
        }
        {
            float mx = wi[0];
#pragma unroll
            for (int j = 1; j < 8; ++j) mx = fmaxf(mx, wi[j]);
            mx = wave_max(mx);
            float sm = 0.f;
#pragma unroll
            for (int j = 0; j < 8; ++j) { wi[j] = __expf(wi[j] - mx); sm += wi[j]; }
            sm = wave_sum(sm);
            const float inv = 1.0f / sm;
#pragma unroll
            for (int j = 0; j < 8; ++j) wi[j] *= inv;
        }
        fft_conj(hr, hi2, lane);
        fft_conj(wr, wi, lane);
#pragma unroll
        for (int j = 0; j < 8; ++j) {
            const float pr = (hr[j] * wr[j] - hi2[j] * wi[j]) * (1.0f / 512.0f);
            const float pi = (hr[j] * wi[j] + hi2[j] * wr[j]) * (1.0f / 512.0f);
            wr[j] = pr; wi[j] = pi;
        }
        fft_fwd(wr, wi, lane);
        // coalesced direct store: wave covers 2 KB contiguous per plane-row
        float* rr = Cre + (i64)t1 * FB + 8 * lane;
        float* ri = Cim + (i64)t1 * FB + 8 * lane;
        *(float4*)&rr[0] = make_float4(wr[0], wr[1], wr[2], wr[3]);
        *(float4*)&rr[4] = make_float4(wr[4], wr[5], wr[6], wr[7]);
        *(float4*)&ri[0] = make_float4(wi[0], wi[1], wi[2], wi[3]);
        *(float4*)&ri[4] = make_float4(wi[4], wi[5], wi[6], wi[7]);
    }
}

// ---------- f32 [t][f] -> f32 [f][t] per plane (final output layout)
__global__ __launch_bounds__(256) void k_transpose_out(const float* __restrict__ C,
                                                       float* __restrict__ O,
                                                       int pbase) {
    __shared__ float ld[64][65];
    const int p = blockIdx.z;
    const float* src = C + (i64)p * PLANE;            // [t][f], row stride FB
    float* dst = O + (i64)(p + pbase) * PLANE;        // [f][t], row stride TB
    const int t0 = blockIdx.x * 64, f0 = blockIdx.y * 64;
    const int tid = threadIdx.x;
    const int lrr = tid >> 4, lc = (tid & 15) * 4;
#pragma unroll
    for (int i = 0; i < 4; ++i) {
        float4 v = *(const float4*)&src[(i64)(t0 + lrr + i * 16) * FB + f0 + lc];
        ld[lc + 0][lrr + i * 16] = v.x;
        ld[lc + 1][lrr + i * 16] = v.y;
        ld[lc + 2][lrr + i * 16] = v.z;
        ld[lc + 3][lrr + i * 16] = v.w;
    }
    __syncthreads();
    const int fr = tid >> 4, tc = (tid & 15) * 4;
#pragma unroll
    for (int i = 0; i < 4; ++i) {
        const int f = fr + i * 16;
        float4 o;
        o.x = ld[f][tc + 0]; o.y = ld[f][tc + 1];
        o.z = ld[f][tc + 2]; o.w = ld[f][tc + 3];
        *(float4*)&dst[(i64)(f0 + f) * TB + t0 + tc] = o;
    }
}

extern "C" void kernel_launch(void* const* d_in, const int* in_sizes, int n_in,
                              void* d_out, int out_size, void* d_ws, size_t ws_size,
                              hipStream_t stream) {
    (void)in_sizes; (void)n_in; (void)out_size; (void)ws_size;
    const float* x = (const float*)d_in[0];
    const float* W1 = (const float*)d_in[1];
    const float* b1 = (const float*)d_in[2];
    const float* W2 = (const float*)d_in[3];
    const float* b2 = (const float*)d_in[4];
    float* out = (float*)d_out;

    char* ws = (char*)d_ws;
    f16* Weff = (f16*)(ws);                               // 512 KB
    float* beff = (float*)(ws + 524288);                  // 4 KB pad
    f16* xh = (f16*)(ws + 528384);                        // 67.1 MB
    f16* logits = (f16*)(ws + 528384 + (i64)67108864);    // 67.1 MB
    float* conv = (float*)(ws + 528384 + (i64)2 * 67108864);  // 67.1 MB (half planes f32)

    // fused linear weights: Weff = W2@W1, beff = W2@b1 + b2
    k_weff<<<dim3(8, 128), dim3(256), 0, stream>>>(W1, W2, Weff);
    k_beff<<<dim3(2), dim3(256), 0, stream>>>(W2, b1, b2, beff);
    // x -> f16 [t][f]
    k_transpose_cvt<<<dim3(4, 8, 256), dim3(256), 0, stream>>>(x, xh);
    // logits = Weff @ X + beff
    k_rgemm<<<dim3(TB / 128, FB / 128, 256), dim3(256), 0, stream>>>(Weff, xh, beff, logits);

    // chunk 0: plane-pairs 0..63 (planes 0..127)
    k_fftconv<<<dim3(32, 64), dim3(256), 0, stream>>>(xh, logits, conv, 0);
    k_transpose_out<<<dim3(4, 8, 128), dim3(256), 0, stream>>>(conv, out, 0);
    // chunk 1: plane-pairs 64..127 (planes 128..255)
    k_fftconv<<<dim3(32, 64), dim3(256), 0, stream>>>(xh, logits, conv, 64);
    k_transpose_out<<<dim3(4, 8, 128), dim3(256), 0, stream>>>(conv, out, 128);
}

// Round 5
// 392.267 us; speedup vs baseline: 3.1387x; 3.1387x over previous
//
#include <hip/hip_runtime.h>
#include <math.h>

#define FB 512
#define TB 256
#define PLANE (FB * TB)
typedef long long i64;
typedef _Float16 f16;
typedef _Float16 f16x8 __attribute__((ext_vector_type(8)));
typedef _Float16 f16x4 __attribute__((ext_vector_type(4)));
typedef float f32x4 __attribute__((ext_vector_type(4)));

#define MFMA16(a, b, c) __builtin_amdgcn_mfma_f32_16x16x32_f16(a, b, c, 0, 0, 0)

// ---------- Weff = W2 @ W1  (f32 accum, f16 out)
__global__ __launch_bounds__(256) void k_weff(const float* __restrict__ W1,
                                              const float* __restrict__ W2,
                                              f16* __restrict__ Weff) {
    const int m = blockIdx.y * 4 + (threadIdx.x >> 6);
    const int k = blockIdx.x * 64 + (threadIdx.x & 63);
    const float* w2r = W2 + (i64)m * FB;
    float acc = 0.f;
#pragma unroll 4
    for (int j = 0; j < FB; ++j) acc = fmaf(w2r[j], W1[(i64)j * FB + k], acc);
    Weff[(i64)m * FB + k] = (f16)acc;
}

// ---------- beff = W2 @ b1 + b2 (f32)
__global__ __launch_bounds__(256) void k_beff(const float* __restrict__ W2,
                                              const float* __restrict__ b1,
                                              const float* __restrict__ b2,
                                              float* __restrict__ beff) {
    const int m = blockIdx.x * 256 + threadIdx.x;
    const float* w2r = W2 + (i64)m * FB;
    float acc = b2[m];
#pragma unroll 4
    for (int k = 0; k < FB; ++k) acc = fmaf(w2r[k], b1[k], acc);
    beff[m] = acc;
}

// ---------- x f32 [f][t] -> xh f16 transposed [t][f], per plane, via LDS
__global__ __launch_bounds__(256) void k_transpose_cvt(const float* __restrict__ X,
                                                       f16* __restrict__ O) {
    __shared__ float ld[64][65];
    const int p = blockIdx.z;
    const float* src = X + (i64)p * PLANE;
    f16* dst = O + (i64)p * PLANE;
    const int f0 = blockIdx.y * 64, t0 = blockIdx.x * 64;
    const int tid = threadIdx.x;
    const int lrr = tid >> 4, lc = (tid & 15) * 4;
#pragma unroll
    for (int i = 0; i < 4; ++i) {
        float4 v = *(const float4*)&src[(i64)(f0 + lrr + i * 16) * TB + t0 + lc];
        ld[lrr + i * 16][lc + 0] = v.x;
        ld[lrr + i * 16][lc + 1] = v.y;
        ld[lrr + i * 16][lc + 2] = v.z;
        ld[lrr + i * 16][lc + 3] = v.w;
    }
    __syncthreads();
    const int tr = tid >> 2, fq = tid & 3;
#pragma unroll
    for (int i = 0; i < 4; ++i) {
        const int fl = fq * 16 + i * 4;
        f16x4 o;
#pragma unroll
        for (int j = 0; j < 4; ++j) o[j] = (f16)ld[fl + j][tr];
        *(f16x4*)&dst[(i64)(t0 + tr) * FB + f0 + fl] = o;
    }
}

// ---------- real MFMA GEMM: Out[t][m] (f16) = sum_k A[m][k]*In[t][k] + bias[m]
__global__ __launch_bounds__(256, 2) void k_rgemm(const f16* __restrict__ A,
                                                  const f16* __restrict__ In,
                                                  const float* __restrict__ bias,
                                                  f16* __restrict__ Out) {
    __shared__ f16 Asx[128][40], Bsx[128][40];
    const int slab = blockIdx.z;
    const f16* Bsrc = In + (i64)slab * PLANE;
    f16* Odst = Out + (i64)slab * PLANE;
    const int t0 = blockIdx.x * 128, m0 = blockIdx.y * 128;
    const int tid = threadIdx.x;
    const int wave = tid >> 6, lane = tid & 63;
    const int wm = wave >> 1, wn = wave & 1;
    const int lr = lane & 15, lg = lane >> 4;
    const int srow = tid >> 2, sgrp = (tid & 3) * 8;

    f32x4 acc[4][4] = {};
    f16x8 nA[2], nB[2];
#pragma unroll
    for (int i = 0; i < 2; ++i) {
        const int row = i * 64 + srow;
        nA[i] = *(const f16x8*)(A + (i64)(m0 + row) * FB + sgrp);
        nB[i] = *(const f16x8*)(Bsrc + (i64)(t0 + row) * FB + sgrp);
    }
#pragma unroll
    for (int i = 0; i < 2; ++i) {
        const int row = i * 64 + srow;
        *(f16x8*)&Asx[row][sgrp] = nA[i];
        *(f16x8*)&Bsx[row][sgrp] = nB[i];
    }
    __syncthreads();

#pragma unroll 1
    for (int kt = 0; kt < 16; ++kt) {
        if (kt < 15) {
            const int k0 = (kt + 1) * 32;
#pragma unroll
            for (int i = 0; i < 2; ++i) {
                const int row = i * 64 + srow;
                nA[i] = *(const f16x8*)(A + (i64)(m0 + row) * FB + k0 + sgrp);
                nB[i] = *(const f16x8*)(Bsrc + (i64)(t0 + row) * FB + k0 + sgrp);
            }
        }
        f16x8 aA[4], bB[4];
#pragma unroll
        for (int mf = 0; mf < 4; ++mf)
            aA[mf] = *(const f16x8*)&Asx[wm * 64 + mf * 16 + lr][lg * 8];
#pragma unroll
        for (int nf = 0; nf < 4; ++nf)
            bB[nf] = *(const f16x8*)&Bsx[wn * 64 + nf * 16 + lr][lg * 8];
#pragma unroll
        for (int nf = 0; nf < 4; ++nf)
#pragma unroll
            for (int mf = 0; mf < 4; ++mf)
                acc[mf][nf] = MFMA16(aA[mf], bB[nf], acc[mf][nf]);
        __syncthreads();
        if (kt < 15) {
#pragma unroll
            for (int i = 0; i < 2; ++i) {
                const int row = i * 64 + srow;
                *(f16x8*)&Asx[row][sgrp] = nA[i];
                *(f16x8*)&Bsx[row][sgrp] = nB[i];
            }
        }
        __syncthreads();
    }

#pragma unroll
    for (int mf = 0; mf < 4; ++mf) {
        const int m = m0 + wm * 64 + mf * 16 + lg * 4;
        const float4 bv = *(const float4*)&bias[m];
        const float bb[4] = {bv.x, bv.y, bv.z, bv.w};
#pragma unroll
        for (int nf = 0; nf < 4; ++nf) {
            const int t = t0 + wn * 64 + nf * 16 + lr;
            f16x4 o;
#pragma unroll
            for (int r = 0; r < 4; ++r) o[r] = (f16)(acc[mf][nf][r] + bb[r]);
            *(f16x4*)&Odst[(i64)t * FB + m] = o;
        }
    }
}

// ================= fused softmax + IDFT/mul/DFT (512-pt FFT per wave) ========
// p = 8*lane + j. DIF (W+) leaves bit-reversed order; pointwise product in
// scrambled order; DIT (W-) consumes rev order, emits natural.
// Twiddles: one sincos per cross stage + constant-angle rotation per j.

#define TWO_PI_OVER_512 0.012271846303085129f
#define R2C 0.70710678118654752f

__device__ __forceinline__ void bfly_dif(float& ar, float& ai, float& br, float& bi,
                                         float wc, float ws) {
    float dr = ar - br, di = ai - bi;
    ar = ar + br; ai = ai + bi;
    br = dr * wc - di * ws;
    bi = dr * ws + di * wc;
}
__device__ __forceinline__ void bfly_dit(float& ar, float& ai, float& br, float& bi,
                                         float wc, float ws) {
    float tr = br * wc - bi * ws;
    float ti = br * ws + bi * wc;
    br = ar - tr; bi = ai - ti;
    ar = ar + tr; ai = ai + ti;
}

// cross DIF stage: result_lo = mine+partner ; result_hi = (partner-mine)*W+
__device__ __forceinline__ void dif_cross2(float re[8], float im[8], int lane, int M,
                                           float mul, float SC, float SS) {
    const bool hi = (lane & M) != 0;
    const float sgn = hi ? -1.f : 1.f;
    const float th0 = TWO_PI_OVER_512 * mul * (float)(8 * (lane & (M - 1)));
    float s0, c0;
    __sincosf(th0, &s0, &c0);
    float c = hi ? c0 : 1.f;
    float s = hi ? s0 : 0.f;
    const float stC = hi ? SC : 1.f;
    const float stS = hi ? SS : 0.f;
#pragma unroll
    for (int j = 0; j < 8; ++j) {
        float pr = __shfl_xor(re[j], M);
        float pi = __shfl_xor(im[j], M);
        float ur = fmaf(sgn, re[j], pr);
        float ui = fmaf(sgn, im[j], pi);
        re[j] = ur * c - ui * s;
        im[j] = ur * s + ui * c;
        float c2 = c * stC - s * stS;
        s = c * stS + s * stC;
        c = c2;
    }
}

// cross DIT stage: own pre-twiddled by W- on hi lanes, then
// result_lo = own' + partner' ; result_hi = partner' - own'
__device__ __forceinline__ void dit_cross2(float re[8], float im[8], int lane, int M,
                                           float mul, float SC, float SS) {
    const bool hi = (lane & M) != 0;
    const float sgn = hi ? -1.f : 1.f;
    const float th0 = TWO_PI_OVER_512 * mul * (float)(8 * (lane & (M - 1)));
    float s0, c0;
    __sincosf(th0, &s0, &c0);
    float c = hi ? c0 : 1.f;
    float s = hi ? s0 : 0.f;     // actual W- = (c, -s); lo lanes (1,0)
    const float stC = hi ? SC : 1.f;
    const float stS = hi ? SS : 0.f;
#pragma unroll
    for (int j = 0; j < 8; ++j) {
        float vr = re[j] * c + im[j] * s;
        float vi = im[j] * c - re[j] * s;
        float pr = __shfl_xor(vr, M);
        float pi = __shfl_xor(vi, M);
        re[j] = fmaf(sgn, vr, pr);
        im[j] = fmaf(sgn, vi, pi);
        float c2 = c * stC - s * stS;
        s = c * stS + s * stC;
        c = c2;
    }
}

// step constants: cos/sin(2*pi*mul/512)
#define C1  0.99992470183914450f
#define S1  0.012271538285719925f
#define C2  0.99969881869620425f
#define S2  0.024541228522912288f
#define C4  0.99879545620517241f
#define S4  0.049067674327418015f
#define C8  0.99518472667219693f
#define S8  0.098017140329560604f
#define C16 0.98078528040323044f
#define S16 0.19509032201612825f
#define C32 0.92387953251128674f
#define S32 0.38268343236508977f

__device__ __forceinline__ void fft_conj(float re[8], float im[8], int lane) { // F+ DIF
    dif_cross2(re, im, lane, 32, 1.f, C1, S1);
    dif_cross2(re, im, lane, 16, 2.f, C2, S2);
    dif_cross2(re, im, lane, 8, 4.f, C4, S4);
    dif_cross2(re, im, lane, 4, 8.f, C8, S8);
    dif_cross2(re, im, lane, 2, 16.f, C16, S16);
    dif_cross2(re, im, lane, 1, 32.f, C32, S32);
    // h=4 (W+ = e^{+i pi/4 * jlo})
    bfly_dif(re[0], im[0], re[4], im[4], 1.f, 0.f);
    bfly_dif(re[1], im[1], re[5], im[5], R2C, R2C);
    bfly_dif(re[2], im[2], re[6], im[6], 0.f, 1.f);
    bfly_dif(re[3], im[3], re[7], im[7], -R2C, R2C);
    // h=2
    bfly_dif(re[0], im[0], re[2], im[2], 1.f, 0.f);
    bfly_dif(re[1], im[1], re[3], im[3], 0.f, 1.f);
    bfly_dif(re[4], im[4], re[6], im[6], 1.f, 0.f);
    bfly_dif(re[5], im[5], re[7], im[7], 0.f, 1.f);
    // h=1
    bfly_dif(re[0], im[0], re[1], im[1], 1.f, 0.f);
    bfly_dif(re[2], im[2], re[3], im[3], 1.f, 0.f);
    bfly_dif(re[4], im[4], re[5], im[5], 1.f, 0.f);
    bfly_dif(re[6], im[6], re[7], im[7], 1.f, 0.f);
}

__device__ __forceinline__ void fft_fwd(float re[8], float im[8], int lane) { // F- DIT
    // h=1
    bfly_dit(re[0], im[0], re[1], im[1], 1.f, 0.f);
    bfly_dit(re[2], im[2], re[3], im[3], 1.f, 0.f);
    bfly_dit(re[4], im[4], re[5], im[5], 1.f, 0.f);
    bfly_dit(re[6], im[6], re[7], im[7], 1.f, 0.f);
    // h=2 (W- = e^{-i pi/2 * (jlo&1)})
    bfly_dit(re[0], im[0], re[2], im[2], 1.f, 0.f);
    bfly_dit(re[1], im[1], re[3], im[3], 0.f, -1.f);
    bfly_dit(re[4], im[4], re[6], im[6], 1.f, 0.f);
    bfly_dit(re[5], im[5], re[7], im[7], 0.f, -1.f);
    // h=4
    bfly_dit(re[0], im[0], re[4], im[4], 1.f, 0.f);
    bfly_dit(re[1], im[1], re[5], im[5], R2C, -R2C);
    bfly_dit(re[2], im[2], re[6], im[6], 0.f, -1.f);
    bfly_dit(re[3], im[3], re[7], im[7], -R2C, -R2C);
    dit_cross2(re, im, lane, 1, 32.f, C32, S32);
    dit_cross2(re, im, lane, 2, 16.f, C16, S16);
    dit_cross2(re, im, lane, 4, 8.f, C8, S8);
    dit_cross2(re, im, lane, 8, 4.f, C4, S4);
    dit_cross2(re, im, lane, 16, 2.f, C2, S2);
    dit_cross2(re, im, lane, 32, 1.f, C1, S1);
}

__device__ __forceinline__ float wave_max(float v) {
#pragma unroll
    for (int m = 1; m <= 32; m <<= 1) v = fmaxf(v, __shfl_xor(v, m));
    return v;
}
__device__ __forceinline__ float wave_sum(float v) {
#pragma unroll
    for (int m = 1; m <= 32; m <<= 1) v += __shfl_xor(v, m);
    return v;
}

// grid (32 t-blocks, 64 plane-pairs per chunk), block 256 (4 waves, 2 seqs each).
// Writes f32 [t][f] into conv scratch (chunk-local planes), fully coalesced.
// NOTE: launch_bounds (256,2) => VGPR cap 256 (NOT 64 — r4's forced-64 spilled
// every FFT array to scratch: 1.7 GB of hidden traffic). it-loop fully unrolls
// so every array index is static (rule #20).
__global__ __launch_bounds__(256, 2) void k_fftconv(const f16* __restrict__ xh,
                                                    const f16* __restrict__ logits,
                                                    float* __restrict__ conv,
                                                    int csbase) {
    const int cs = blockIdx.y + csbase;
    const int b = cs >> 4, d = cs & 15;
    const int pre = b * 32 + d;
    const int pim = pre + 16;
    const int chunkoff = (csbase >> 6) * 128;   // plane offset of this chunk
    const int t0 = blockIdx.x * 8;
    const int tid = threadIdx.x;
    const int wave = tid >> 6, lane = tid & 63;

    float* Cre = conv + (i64)(pre - chunkoff) * PLANE;
    float* Cim = conv + (i64)(pim - chunkoff) * PLANE;

#pragma unroll
    for (int it = 0; it < 2; ++it) {
        const int t1 = t0 + wave * 2 + it;
        const i64 row = (i64)t1 * FB + lane * 8;
        const f16x8 vhr = *(const f16x8*)(xh + (i64)pre * PLANE + row);
        const f16x8 vhi = *(const f16x8*)(xh + (i64)pim * PLANE + row);
        const f16x8 vwr = *(const f16x8*)(logits + (i64)pre * PLANE + row);
        const f16x8 vwi = *(const f16x8*)(logits + (i64)pim * PLANE + row);
        float hr[8], hi2[8], wr[8], wi[8];
#pragma unroll
        for (int j = 0; j < 8; ++j) {
            hr[j] = (float)vhr[j];
            hi2[j] = (float)vhi[j];
            wr[j] = (float)vwr[j];
            wi[j] = (float)vwi[j];
        }
        // softmax along f for each component plane
        {
            float mx = wr[0];
#pragma unroll
            for (int j = 1; j < 8; ++j) mx = fmaxf(mx, wr[j]);
            mx = wave_max(mx);
            float sm = 0.f;
#pragma unroll
            for (int j = 0; j < 8; ++j) { wr[j] = __expf(wr[j] - mx); sm += wr[j]; }
            sm = wave_sum(sm);
            const float inv = 1.0f / sm;
#pragma unroll
            for (int j = 0; j < 8; ++j) wr[j] *= inv;
        }
        {
            float mx = wi[0];
#pragma unroll
            for (int j = 1; j < 8; ++j) mx = fmaxf(mx, wi[j]);
            mx = wave_max(mx);
            float sm = 0.f;
#pragma unroll
            for (int j = 0; j < 8; ++j) { wi[j] = __expf(wi[j] - mx); sm += wi[j]; }
            sm = wave_sum(sm);
            const float inv = 1.0f / sm;
#pragma unroll
            for (int j = 0; j < 8; ++j) wi[j] *= inv;
        }
        fft_conj(hr, hi2, lane);
        fft_conj(wr, wi, lane);
#pragma unroll
        for (int j = 0; j < 8; ++j) {
            const float pr = (hr[j] * wr[j] - hi2[j] * wi[j]) * (1.0f / 512.0f);
            const float pi = (hr[j] * wi[j] + hi2[j] * wr[j]) * (1.0f / 512.0f);
            wr[j] = pr; wi[j] = pi;
        }
        fft_fwd(wr, wi, lane);
        // coalesced direct store: wave covers 2 KB contiguous per plane-row
        float* rr = Cre + (i64)t1 * FB + 8 * lane;
        float* ri = Cim + (i64)t1 * FB + 8 * lane;
        *(float4*)&rr[0] = make_float4(wr[0], wr[1], wr[2], wr[3]);
        *(float4*)&rr[4] = make_float4(wr[4], wr[5], wr[6], wr[7]);
        *(float4*)&ri[0] = make_float4(wi[0], wi[1], wi[2], wi[3]);
        *(float4*)&ri[4] = make_float4(wi[4], wi[5], wi[6], wi[7]);
    }
}

// ---------- f32 [t][f] -> f32 [f][t] per plane (final output layout)
__global__ __launch_bounds__(256) void k_transpose_out(const float* __restrict__ C,
                                                       float* __restrict__ O,
                                                       int pbase) {
    __shared__ float ld[64][65];
    const int p = blockIdx.z;
    const float* src = C + (i64)p * PLANE;            // [t][f], row stride FB
    float* dst = O + (i64)(p + pbase) * PLANE;        // [f][t], row stride TB
    const int t0 = blockIdx.x * 64, f0 = blockIdx.y * 64;
    const int tid = threadIdx.x;
    const int lrr = tid >> 4, lc = (tid & 15) * 4;
#pragma unroll
    for (int i = 0; i < 4; ++i) {
        float4 v = *(const float4*)&src[(i64)(t0 + lrr + i * 16) * FB + f0 + lc];
        ld[lc + 0][lrr + i * 16] = v.x;
        ld[lc + 1][lrr + i * 16] = v.y;
        ld[lc + 2][lrr + i * 16] = v.z;
        ld[lc + 3][lrr + i * 16] = v.w;
    }
    __syncthreads();
    const int fr = tid >> 4, tc = (tid & 15) * 4;
#pragma unroll
    for (int i = 0; i < 4; ++i) {
        const int f = fr + i * 16;
        float4 o;
        o.x = ld[f][tc + 0]; o.y = ld[f][tc + 1];
        o.z = ld[f][tc + 2]; o.w = ld[f][tc + 3];
        *(float4*)&dst[(i64)(f0 + f) * TB + t0 + tc] = o;
    }
}

extern "C" void kernel_launch(void* const* d_in, const int* in_sizes, int n_in,
                              void* d_out, int out_size, void* d_ws, size_t ws_size,
                              hipStream_t stream) {
    (void)in_sizes; (void)n_in; (void)out_size; (void)ws_size;
    const float* x = (const float*)d_in[0];
    const float* W1 = (const float*)d_in[1];
    const float* b1 = (const float*)d_in[2];
    const float* W2 = (const float*)d_in[3];
    const float* b2 = (const float*)d_in[4];
    float* out = (float*)d_out;

    char* ws = (char*)d_ws;
    f16* Weff = (f16*)(ws);                               // 512 KB
    float* beff = (float*)(ws + 524288);                  // 4 KB pad
    f16* xh = (f16*)(ws + 528384);                        // 67.1 MB
    f16* logits = (f16*)(ws + 528384 + (i64)67108864);    // 67.1 MB
    float* conv = (float*)(ws + 528384 + (i64)2 * 67108864);  // 67.1 MB (half planes f32)

    // fused linear weights: Weff = W2@W1, beff = W2@b1 + b2
    k_weff<<<dim3(8, 128), dim3(256), 0, stream>>>(W1, W2, Weff);
    k_beff<<<dim3(2), dim3(256), 0, stream>>>(W2, b1, b2, beff);
    // x -> f16 [t][f]
    k_transpose_cvt<<<dim3(4, 8, 256), dim3(256), 0, stream>>>(x, xh);
    // logits = Weff @ X + beff
    k_rgemm<<<dim3(TB / 128, FB / 128, 256), dim3(256), 0, stream>>>(Weff, xh, beff, logits);

    // chunk 0: plane-pairs 0..63 (planes 0..127)
    k_fftconv<<<dim3(32, 64), dim3(256), 0, stream>>>(xh, logits, conv, 0);
    k_transpose_out<<<dim3(4, 8, 128), dim3(256), 0, stream>>>(conv, out, 0);
    // chunk 1: plane-pairs 64..127 (planes 128..255)
    k_fftconv<<<dim3(32, 64), dim3(256), 0, stream>>>(xh, logits, conv, 64);
    k_transpose_out<<<dim3(4, 8, 128), dim3(256), 0, stream>>>(conv, out, 128);
}

// Round 6
// 327.253 us; speedup vs baseline: 3.7623x; 1.1987x over previous
//
#include <hip/hip_runtime.h>
#include <math.h>

#define FB 512
#define TB 256
#define PLANE (FB * TB)
typedef long long i64;
typedef _Float16 f16;
typedef _Float16 f16x8 __attribute__((ext_vector_type(8)));
typedef _Float16 f16x4 __attribute__((ext_vector_type(4)));
typedef float f32x4 __attribute__((ext_vector_type(4)));

#define MFMA16(a, b, c) __builtin_amdgcn_mfma_f32_16x16x32_f16(a, b, c, 0, 0, 0)

// ---------- Weff = W2 @ W1  (f32 accum, f16 out)
__global__ __launch_bounds__(256) void k_weff(const float* __restrict__ W1,
                                              const float* __restrict__ W2,
                                              f16* __restrict__ Weff) {
    const int m = blockIdx.y * 4 + (threadIdx.x >> 6);
    const int k = blockIdx.x * 64 + (threadIdx.x & 63);
    const float* w2r = W2 + (i64)m * FB;
    float acc = 0.f;
#pragma unroll 4
    for (int j = 0; j < FB; ++j) acc = fmaf(w2r[j], W1[(i64)j * FB + k], acc);
    Weff[(i64)m * FB + k] = (f16)acc;
}

// ---------- beff = W2 @ b1 + b2 (f32)
__global__ __launch_bounds__(256) void k_beff(const float* __restrict__ W2,
                                              const float* __restrict__ b1,
                                              const float* __restrict__ b2,
                                              float* __restrict__ beff) {
    const int m = blockIdx.x * 256 + threadIdx.x;
    const float* w2r = W2 + (i64)m * FB;
    float acc = b2[m];
#pragma unroll 4
    for (int k = 0; k < FB; ++k) acc = fmaf(w2r[k], b1[k], acc);
    beff[m] = acc;
}

// ---------- x f32 [f][t] -> xh f16 transposed [t][f], per plane, via LDS
__global__ __launch_bounds__(256) void k_transpose_cvt(const float* __restrict__ X,
                                                       f16* __restrict__ O) {
    __shared__ float ld[64][65];
    const int p = blockIdx.z;
    const float* src = X + (i64)p * PLANE;
    f16* dst = O + (i64)p * PLANE;
    const int f0 = blockIdx.y * 64, t0 = blockIdx.x * 64;
    const int tid = threadIdx.x;
    const int lrr = tid >> 4, lc = (tid & 15) * 4;
#pragma unroll
    for (int i = 0; i < 4; ++i) {
        float4 v = *(const float4*)&src[(i64)(f0 + lrr + i * 16) * TB + t0 + lc];
        ld[lrr + i * 16][lc + 0] = v.x;
        ld[lrr + i * 16][lc + 1] = v.y;
        ld[lrr + i * 16][lc + 2] = v.z;
        ld[lrr + i * 16][lc + 3] = v.w;
    }
    __syncthreads();
    const int tr = tid >> 2, fq = tid & 3;
#pragma unroll
    for (int i = 0; i < 4; ++i) {
        const int fl = fq * 16 + i * 4;
        f16x4 o;
#pragma unroll
        for (int j = 0; j < 4; ++j) o[j] = (f16)ld[fl + j][tr];
        *(f16x4*)&dst[(i64)(t0 + tr) * FB + f0 + fl] = o;
    }
}

// ---------- real MFMA GEMM: Out[t][m] (f16) = sum_k A[m][k]*In[t][k] + bias[m]
__global__ __launch_bounds__(256, 2) void k_rgemm(const f16* __restrict__ A,
                                                  const f16* __restrict__ In,
                                                  const float* __restrict__ bias,
                                                  f16* __restrict__ Out) {
    __shared__ f16 Asx[128][40], Bsx[128][40];
    const int slab = blockIdx.z;
    const f16* Bsrc = In + (i64)slab * PLANE;
    f16* Odst = Out + (i64)slab * PLANE;
    const int t0 = blockIdx.x * 128, m0 = blockIdx.y * 128;
    const int tid = threadIdx.x;
    const int wave = tid >> 6, lane = tid & 63;
    const int wm = wave >> 1, wn = wave & 1;
    const int lr = lane & 15, lg = lane >> 4;
    const int srow = tid >> 2, sgrp = (tid & 3) * 8;

    f32x4 acc[4][4] = {};
    f16x8 nA[2], nB[2];
#pragma unroll
    for (int i = 0; i < 2; ++i) {
        const int row = i * 64 + srow;
        nA[i] = *(const f16x8*)(A + (i64)(m0 + row) * FB + sgrp);
        nB[i] = *(const f16x8*)(Bsrc + (i64)(t0 + row) * FB + sgrp);
    }
#pragma unroll
    for (int i = 0; i < 2; ++i) {
        const int row = i * 64 + srow;
        *(f16x8*)&Asx[row][sgrp] = nA[i];
        *(f16x8*)&Bsx[row][sgrp] = nB[i];
    }
    __syncthreads();

#pragma unroll 1
    for (int kt = 0; kt < 16; ++kt) {
        if (kt < 15) {
            const int k0 = (kt + 1) * 32;
#pragma unroll
            for (int i = 0; i < 2; ++i) {
                const int row = i * 64 + srow;
                nA[i] = *(const f16x8*)(A + (i64)(m0 + row) * FB + k0 + sgrp);
                nB[i] = *(const f16x8*)(Bsrc + (i64)(t0 + row) * FB + k0 + sgrp);
            }
        }
        f16x8 aA[4], bB[4];
#pragma unroll
        for (int mf = 0; mf < 4; ++mf)
            aA[mf] = *(const f16x8*)&Asx[wm * 64 + mf * 16 + lr][lg * 8];
#pragma unroll
        for (int nf = 0; nf < 4; ++nf)
            bB[nf] = *(const f16x8*)&Bsx[wn * 64 + nf * 16 + lr][lg * 8];
#pragma unroll
        for (int nf = 0; nf < 4; ++nf)
#pragma unroll
            for (int mf = 0; mf < 4; ++mf)
                acc[mf][nf] = MFMA16(aA[mf], bB[nf], acc[mf][nf]);
        __syncthreads();
        if (kt < 15) {
#pragma unroll
            for (int i = 0; i < 2; ++i) {
                const int row = i * 64 + srow;
                *(f16x8*)&Asx[row][sgrp] = nA[i];
                *(f16x8*)&Bsx[row][sgrp] = nB[i];
            }
        }
        __syncthreads();
    }

#pragma unroll
    for (int mf = 0; mf < 4; ++mf) {
        const int m = m0 + wm * 64 + mf * 16 + lg * 4;
        const float4 bv = *(const float4*)&bias[m];
        const float bb[4] = {bv.x, bv.y, bv.z, bv.w};
#pragma unroll
        for (int nf = 0; nf < 4; ++nf) {
            const int t = t0 + wn * 64 + nf * 16 + lr;
            f16x4 o;
#pragma unroll
            for (int r = 0; r < 4; ++r) o[r] = (f16)(acc[mf][nf][r] + bb[r]);
            *(f16x4*)&Odst[(i64)t * FB + m] = o;
        }
    }
}

// ================= fused softmax + conjFFT/mul/FFT, radix-8 three-step =======
// Arrangement invariant: value z[p] lives at (lane = p%64, reg = p/64).
// fft512<SGN>: natural-order in -> natural-order out (digit reversal absorbed
// by the two LDS transposes' read assignments). SGN=+1: conjDFT; SGN=-1: DFT.
// LDS transposes are wave-private (no barriers); stride-9 rows => <=2-way bank
// aliasing (free). Derivation: p=u+64v, k=m+8n+64s;
//   X[m+8n+64s] = DFT8_a{ e^(s2pi*an/64) DFT8_b{ w^(um) DFT8_v{x} } }.

#define TWO_PI_OVER_512 0.012271846303085129f
#define TWO_PI_OVER_64 0.0981747704246810387f
#define R2C 0.70710678118654752f

template <int SGN>
__device__ __forceinline__ void fft8(float xr[8], float xi[8]) {
    const float sg = (float)SGN;   // W8 = e^{SGN*i*2pi/8}
    float t0r = xr[0] + xr[4], t0i = xi[0] + xi[4];
    float u0r = xr[0] - xr[4], u0i = xi[0] - xi[4];
    float t1r = xr[1] + xr[5], t1i = xi[1] + xi[5];
    float d1r = xr[1] - xr[5], d1i = xi[1] - xi[5];
    float u1r = R2C * (d1r - sg * d1i), u1i = R2C * (sg * d1r + d1i);
    float t2r = xr[2] + xr[6], t2i = xi[2] + xi[6];
    float d2r = xr[2] - xr[6], d2i = xi[2] - xi[6];
    float u2r = -sg * d2i, u2i = sg * d2r;
    float t3r = xr[3] + xr[7], t3i = xi[3] + xi[7];
    float d3r = xr[3] - xr[7], d3i = xi[3] - xi[7];
    float u3r = -R2C * (d3r + sg * d3i), u3i = R2C * (sg * d3r - d3i);
    float p0r = t0r + t2r, p0i = t0i + t2i, q0r = t0r - t2r, q0i = t0i - t2i;
    float p1r = t1r + t3r, p1i = t1i + t3i;
    float q1r = -sg * (t1i - t3i), q1i = sg * (t1r - t3r);
    float p2r = u0r + u2r, p2i = u0i + u2i, q2r = u0r - u2r, q2i = u0i - u2i;
    float p3r = u1r + u3r, p3i = u1i + u3i;
    float q3r = -sg * (u1i - u3i), q3i = sg * (u1r - u3r);
    xr[0] = p0r + p1r; xi[0] = p0i + p1i;
    xr[4] = p0r - p1r; xi[4] = p0i - p1i;
    xr[2] = q0r + q1r; xi[2] = q0i + q1i;
    xr[6] = q0r - q1r; xi[6] = q0i - q1i;
    xr[1] = p2r + p3r; xi[1] = p2i + p3i;
    xr[5] = p2r - p3r; xi[5] = p2i - p3i;
    xr[3] = q2r + q3r; xi[3] = q2i + q3i;
    xr[7] = q2r - q3r; xi[7] = q2i - q3i;
}

template <int SGN>
__device__ __forceinline__ void fft512(float xr[8], float xi[8], int lane,
                                       float* __restrict__ LR,
                                       float* __restrict__ LI) {
    const float sg = (float)SGN;
    // step 1: DFT8 over v (regs)
    fft8<SGN>(xr, xi);
    // step 2: twiddle w^{u*m}, w = e^{SGN*2pi*i*lane/512}
    {
        float s1, c1;
        __sincosf((float)lane * TWO_PI_OVER_512, &s1, &c1);
        s1 *= sg;
        float wrc = c1, wic = s1;
#pragma unroll
        for (int m = 1; m < 8; ++m) {
            float ar = xr[m], ai = xi[m];
            xr[m] = ar * wrc - ai * wic;
            xi[m] = ar * wic + ai * wrc;
            float nr = wrc * c1 - wic * s1;
            wic = wrc * s1 + wic * c1;
            wrc = nr;
        }
    }
    // transpose 1: (lane=u=a+8b, reg=m) -> (lane=a+8m, reg=b)
#pragma unroll
    for (int m = 0; m < 8; ++m) { LR[lane * 9 + m] = xr[m]; LI[lane * 9 + m] = xi[m]; }
    {
        const int a = lane & 7, m = lane >> 3;
#pragma unroll
        for (int b = 0; b < 8; ++b) {
            xr[b] = LR[(a + 8 * b) * 9 + m];
            xi[b] = LI[(a + 8 * b) * 9 + m];
        }
    }
    // step 3: DFT8 over b
    fft8<SGN>(xr, xi);
    // step 4: twiddle e^{SGN*2pi*i*a*n/64}, a = lane&7
    {
        float s2, c2;
        __sincosf((float)(lane & 7) * TWO_PI_OVER_64, &s2, &c2);
        s2 *= sg;
        float wrc = c2, wic = s2;
#pragma unroll
        for (int n = 1; n < 8; ++n) {
            float ar = xr[n], ai = xi[n];
            xr[n] = ar * wrc - ai * wic;
            xi[n] = ar * wic + ai * wrc;
            float nr = wrc * c2 - wic * s2;
            wic = wrc * s2 + wic * c2;
            wrc = nr;
        }
    }
    // transpose 2: (lane=a+8m, reg=n) -> (lane=m+8n, reg=a)
#pragma unroll
    for (int n = 0; n < 8; ++n) { LR[lane * 9 + n] = xr[n]; LI[lane * 9 + n] = xi[n]; }
    {
        const int m2 = lane & 7, n2 = lane >> 3;
#pragma unroll
        for (int a = 0; a < 8; ++a) {
            xr[a] = LR[(a + 8 * m2) * 9 + n2];
            xi[a] = LI[(a + 8 * m2) * 9 + n2];
        }
    }
    // step 5: DFT8 over a -> X[lane + 64*reg]
    fft8<SGN>(xr, xi);
}

__device__ __forceinline__ float wave_max(float v) {
#pragma unroll
    for (int m = 1; m <= 32; m <<= 1) v = fmaxf(v, __shfl_xor(v, m));
    return v;
}
__device__ __forceinline__ float wave_sum(float v) {
#pragma unroll
    for (int m = 1; m <= 32; m <<= 1) v += __shfl_xor(v, m);
    return v;
}

// grid (32 t-blocks, 64 plane-pairs per chunk), block 256 (4 waves, 2 seqs each)
// All global access at element stride 64: per-instruction coalesced
// (f16 loads: 128B/wave; f32 stores: 256B/wave). Writes f32 [t][f] chunk scratch.
__global__ __launch_bounds__(256, 2) void k_fftconv(const f16* __restrict__ xh,
                                                    const f16* __restrict__ logits,
                                                    float* __restrict__ conv,
                                                    int csbase) {
    __shared__ float LDSR[4][576], LDSI[4][576];
    const int cs = blockIdx.y + csbase;
    const int b = cs >> 4, d = cs & 15;
    const int pre = b * 32 + d;
    const int pim = pre + 16;
    const int chunkoff = (csbase >> 6) * 128;
    const int t0 = blockIdx.x * 8;
    const int tid = threadIdx.x;
    const int wave = tid >> 6, lane = tid & 63;
    float* LR = LDSR[wave];
    float* LI = LDSI[wave];

    const f16* Hre = xh + (i64)pre * PLANE;
    const f16* Him = xh + (i64)pim * PLANE;
    const f16* Wre = logits + (i64)pre * PLANE;
    const f16* Wim = logits + (i64)pim * PLANE;
    float* Cre = conv + (i64)(pre - chunkoff) * PLANE;
    float* Cim = conv + (i64)(pim - chunkoff) * PLANE;

#pragma unroll
    for (int it = 0; it < 2; ++it) {
        const int t1 = t0 + wave * 2 + it;
        const i64 rb = (i64)t1 * FB + lane;
        float hr[8], hi2[8], wr[8], wi[8];
#pragma unroll
        for (int j = 0; j < 8; ++j) {
            hr[j] = (float)Hre[rb + 64 * j];
            hi2[j] = (float)Him[rb + 64 * j];
            wr[j] = (float)Wre[rb + 64 * j];
            wi[j] = (float)Wim[rb + 64 * j];
        }
        // softmax along f (any arrangement: full-wave reduction)
        {
            float mx = wr[0];
#pragma unroll
            for (int j = 1; j < 8; ++j) mx = fmaxf(mx, wr[j]);
            mx = wave_max(mx);
            float sm = 0.f;
#pragma unroll
            for (int j = 0; j < 8; ++j) { wr[j] = __expf(wr[j] - mx); sm += wr[j]; }
            sm = wave_sum(sm);
            const float inv = 1.0f / sm;
#pragma unroll
            for (int j = 0; j < 8; ++j) wr[j] *= inv;
        }
        {
            float mx = wi[0];
#pragma unroll
            for (int j = 1; j < 8; ++j) mx = fmaxf(mx, wi[j]);
            mx = wave_max(mx);
            float sm = 0.f;
#pragma unroll
            for (int j = 0; j < 8; ++j) { wi[j] = __expf(wi[j] - mx); sm += wi[j]; }
            sm = wave_sum(sm);
            const float inv = 1.0f / sm;
#pragma unroll
            for (int j = 0; j < 8; ++j) wi[j] *= inv;
        }
        // S1 = conjDFT(h), S2 = conjDFT(w); P = S1*S2/512; out = DFT(P)
        fft512<1>(hr, hi2, lane, LR, LI);
        fft512<1>(wr, wi, lane, LR, LI);
#pragma unroll
        for (int j = 0; j < 8; ++j) {
            const float pr = (hr[j] * wr[j] - hi2[j] * wi[j]) * (1.0f / 512.0f);
            const float pi = (hr[j] * wi[j] + hi2[j] * wr[j]) * (1.0f / 512.0f);
            wr[j] = pr; wi[j] = pi;
        }
        fft512<-1>(wr, wi, lane, LR, LI);
#pragma unroll
        for (int s = 0; s < 8; ++s) {
            Cre[rb + 64 * s] = wr[s];
            Cim[rb + 64 * s] = wi[s];
        }
    }
}

// ---------- f32 [t][f] -> f32 [f][t] per plane (final output layout)
__global__ __launch_bounds__(256) void k_transpose_out(const float* __restrict__ C,
                                                       float* __restrict__ O,
                                                       int pbase) {
    __shared__ float ld[64][65];
    const int p = blockIdx.z;
    const float* src = C + (i64)p * PLANE;            // [t][f], row stride FB
    float* dst = O + (i64)(p + pbase) * PLANE;        // [f][t], row stride TB
    const int t0 = blockIdx.x * 64, f0 = blockIdx.y * 64;
    const int tid = threadIdx.x;
    const int lrr = tid >> 4, lc = (tid & 15) * 4;
#pragma unroll
    for (int i = 0; i < 4; ++i) {
        float4 v = *(const float4*)&src[(i64)(t0 + lrr + i * 16) * FB + f0 + lc];
        ld[lc + 0][lrr + i * 16] = v.x;
        ld[lc + 1][lrr + i * 16] = v.y;
        ld[lc + 2][lrr + i * 16] = v.z;
        ld[lc + 3][lrr + i * 16] = v.w;
    }
    __syncthreads();
    const int fr = tid >> 4, tc = (tid & 15) * 4;
#pragma unroll
    for (int i = 0; i < 4; ++i) {
        const int f = fr + i * 16;
        float4 o;
        o.x = ld[f][tc + 0]; o.y = ld[f][tc + 1];
        o.z = ld[f][tc + 2]; o.w = ld[f][tc + 3];
        *(float4*)&dst[(i64)(f0 + f) * TB + t0 + tc] = o;
    }
}

extern "C" void kernel_launch(void* const* d_in, const int* in_sizes, int n_in,
                              void* d_out, int out_size, void* d_ws, size_t ws_size,
                              hipStream_t stream) {
    (void)in_sizes; (void)n_in; (void)out_size; (void)ws_size;
    const float* x = (const float*)d_in[0];
    const float* W1 = (const float*)d_in[1];
    const float* b1 = (const float*)d_in[2];
    const float* W2 = (const float*)d_in[3];
    const float* b2 = (const float*)d_in[4];
    float* out = (float*)d_out;

    char* ws = (char*)d_ws;
    f16* Weff = (f16*)(ws);                               // 512 KB
    float* beff = (float*)(ws + 524288);                  // 4 KB pad
    f16* xh = (f16*)(ws + 528384);                        // 67.1 MB
    f16* logits = (f16*)(ws + 528384 + (i64)67108864);    // 67.1 MB
    float* conv = (float*)(ws + 528384 + (i64)2 * 67108864);  // 67.1 MB (half planes f32)

    // fused linear weights: Weff = W2@W1, beff = W2@b1 + b2
    k_weff<<<dim3(8, 128), dim3(256), 0, stream>>>(W1, W2, Weff);
    k_beff<<<dim3(2), dim3(256), 0, stream>>>(W2, b1, b2, beff);
    // x -> f16 [t][f]
    k_transpose_cvt<<<dim3(4, 8, 256), dim3(256), 0, stream>>>(x, xh);
    // logits = Weff @ X + beff
    k_rgemm<<<dim3(TB / 128, FB / 128, 256), dim3(256), 0, stream>>>(Weff, xh, beff, logits);

    // chunk 0: plane-pairs 0..63 (planes 0..127)
    k_fftconv<<<dim3(32, 64), dim3(256), 0, stream>>>(xh, logits, conv, 0);
    k_transpose_out<<<dim3(4, 8, 128), dim3(256), 0, stream>>>(conv, out, 0);
    // chunk 1: plane-pairs 64..127 (planes 128..255)
    k_fftconv<<<dim3(32, 64), dim3(256), 0, stream>>>(xh, logits, conv, 64);
    k_transpose_out<<<dim3(4, 8, 128), dim3(256), 0, stream>>>(conv, out, 128);
}